// Round 7
// baseline (836.277 us; speedup 1.0000x reference)
//
#include <hip/hip_runtime.h>
#include <hip/hip_bf16.h>
#include <stdint.h>

#define NB 400
#define NC 151
#define DX 4096
#define DE 200
#define DP 128
#define DH 512
#define KREP 4424   // 4096 + 200 + 128
#define TAILW 328   // DE + DP
#define MPAD 416    // 13*32 rows, padded
#define SPLITK 8
#define TILES1 139  // ceil(4424/32) - GEMM1 full K
#define TILES2 132  // 4224/32     - GEMM2a label-independent K
#define SLOTS 7     // 7*64 = 448 >= 400
#define SKSTRIDE 152
#define NGB 1664    // gemm blocks per phase: 16 n * 13 m * 8 z

#define CSW(x, y) do { uint64_t _hi = (x) > (y) ? (x) : (y); \
                       uint64_t _lo = (x) > (y) ? (y) : (x); \
                       (x) = _hi; (y) = _lo; } while (0)

__device__ __forceinline__ uint32_t f2ord(float f) {
  uint32_t u = __float_as_uint(f);
  return (u & 0x80000000u) ? ~u : (u | 0x80000000u);
}

// ---------------------------------------------------------------------------
// k_embed: softmax(logits) @ obj_embed_w and pos path -> packed tail1 =
// [obj_embed(200) | pos_embed(128)]. Rows 400..415 zero (pad for float4).
// ---------------------------------------------------------------------------
__global__ __launch_bounds__(256) void k_embed(
    const float* __restrict__ logits, const float* __restrict__ obj_embed_w,
    const float* __restrict__ pos_input, const float* __restrict__ w_pos1,
    const float* __restrict__ b_pos1, const float* __restrict__ bn_gamma,
    const float* __restrict__ bn_beta, const float* __restrict__ bn_mean,
    const float* __restrict__ bn_var, const float* __restrict__ w_pos2,
    const float* __restrict__ b_pos2, float* __restrict__ tail1) {
  int r = blockIdx.x, t = threadIdx.x;
  if (r >= NB) {
    if (t < TAILW) tail1[r * TAILW + t] = 0.f;
    return;
  }
  __shared__ float p[NC];
  __shared__ float red[256];
  __shared__ float hb[32];

  float v = (t < NC) ? logits[r * NC + t] : -INFINITY;
  red[t] = v; __syncthreads();
  for (int s = 128; s > 0; s >>= 1) { if (t < s) red[t] = fmaxf(red[t], red[t + s]); __syncthreads(); }
  float m = red[0]; __syncthreads();
  float e = (t < NC) ? expf(v - m) : 0.f;
  red[t] = e; __syncthreads();
  for (int s = 128; s > 0; s >>= 1) { if (t < s) red[t] += red[t + s]; __syncthreads(); }
  float sum = red[0];
  if (t < NC) p[t] = e / sum;

  if (t < 32) {
    float acc = b_pos1[t];
    for (int k = 0; k < 9; k++) acc += pos_input[r * 9 + k] * w_pos1[k * 32 + t];
    acc = (acc - bn_mean[t]) / sqrtf(bn_var[t] + 1e-5f) * bn_gamma[t] + bn_beta[t];
    hb[t] = acc;
  }
  __syncthreads();

  if (t < DE) {
    float acc = 0.f;
    for (int k = 0; k < NC; k++) acc += p[k] * obj_embed_w[k * DE + t];
    tail1[r * TAILW + t] = acc;
  }
  if (t < DP) {
    float acc = b_pos2[t];
    for (int k = 0; k < 32; k++) acc += hb[k] * w_pos2[k * DP + t];
    tail1[r * TAILW + DE + t] = fmaxf(acc, 0.f);
  }
}

// ---------------------------------------------------------------------------
// gemm_body: split-K partial GEMM tile, 32(M)x32(N), BK=32, 2x2 microtile.
// 1664 blocks/phase (16 n, 13 m, 8 z) for latency hiding. toff selects tail
// mapping (0: full tail1; DE: pos-only segment for GEMM2a).
// ---------------------------------------------------------------------------
__device__ __forceinline__ void gemm_body(
    const float* __restrict__ x, const float* __restrict__ tail,
    const float* __restrict__ w, float* __restrict__ part,
    int bid, int tiles, int toff) {
  __shared__ __align__(16) float As[32][36];
  __shared__ __align__(16) float Bs[32][36];
  int tid = threadIdx.x;
  int n0 = (bid & 15) * 32, m0 = ((bid >> 4) % 13) * 32;
  int z = bid / 208;
  int tbeg = (z * tiles) / SPLITK, tend = ((z + 1) * tiles) / SPLITK;
  int ty = tid >> 4, tx = tid & 15;
  int a_r = tid >> 3, a_c = (tid & 7) << 2;
  float acc00 = 0.f, acc01 = 0.f, acc10 = 0.f, acc11 = 0.f;

  auto loadA = [&](int t) -> float4 {
    int k = t * 32 + a_c;
    int row = m0 + a_r;
    float4 v = {0, 0, 0, 0};
    if (k < KREP) {
      if (k < DX) { if (row < NB) v = *(const float4*)&x[(size_t)row * DX + k]; }
      else v = *(const float4*)&tail[row * TAILW + toff + (k - DX)];
    }
    return v;
  };
  auto loadB = [&](int t) -> float4 {
    int k = t * 32 + a_r;
    float4 v = {0, 0, 0, 0};
    if (k < KREP) v = *(const float4*)&w[(size_t)k * DH + n0 + a_c];
    return v;
  };

  float4 pa = loadA(tbeg), pb = loadB(tbeg);
  for (int t = tbeg; t < tend; t++) {
    __syncthreads();
    *(float4*)&As[a_r][a_c] = pa;
    *(float4*)&Bs[a_r][a_c] = pb;
    __syncthreads();
    if (t + 1 < tend) { pa = loadA(t + 1); pb = loadB(t + 1); }
#pragma unroll
    for (int k4 = 0; k4 < 8; k4++) {
      float4 av0 = *(float4*)&As[ty * 2][k4 * 4];
      float4 av1 = *(float4*)&As[ty * 2 + 1][k4 * 4];
#pragma unroll
      for (int j = 0; j < 4; j++) {
        float2 bv = *(float2*)&Bs[k4 * 4 + j][tx * 2];
        float x0 = (&av0.x)[j], x1 = (&av1.x)[j];
        acc00 += x0 * bv.x; acc01 += x0 * bv.y;
        acc10 += x1 * bv.x; acc11 += x1 * bv.y;
      }
    }
  }
  int row0 = m0 + ty * 2, col = n0 + tx * 2;
  float* base = part + (size_t)z * NB * DH;
  if (row0 < NB)     { float2 v = {acc00, acc01}; *(float2*)&base[row0 * DH + col] = v; }
  if (row0 + 1 < NB) { float2 v = {acc10, acc11}; *(float2*)&base[(row0 + 1) * DH + col] = v; }
}

// ---------------------------------------------------------------------------
// k_g1ov: blocks 0..1663 = GEMM1 partials (A=[x|tail1], w_lin); blocks
// 1664..1814 = IoU>=0.5 bit matrix per class.
// ---------------------------------------------------------------------------
__global__ __launch_bounds__(256) void k_g1ov(
    const float* __restrict__ x, const float* __restrict__ tail1,
    const float* __restrict__ w_lin, float* __restrict__ part,
    const float* __restrict__ boxes, uint64_t* __restrict__ ov_bits) {
  int bid = blockIdx.x;
  if (bid >= NGB) {
    int c = bid - NGB;
    int t = threadIdx.x;
    __shared__ float4 bx[NB];
    const float4* bp4 = (const float4*)boxes;
    for (int j = t; j < NB; j += 256) bx[j] = bp4[j * NC + c];
    __syncthreads();
    int wave = t >> 6, lane = t & 63;
    for (int b = wave; b < NB; b += 4) {
      float4 A = bx[b];
      float areaA = (A.z - A.x + 1.f) * (A.w - A.y + 1.f);
      for (int chunk = 0; chunk < 7; chunk++) {
        int j = chunk * 64 + lane;
        bool ov = false;
        if (j < NB) {
          float4 B = bx[j];
          float x1 = fmaxf(A.x, B.x), y1 = fmaxf(A.y, B.y);
          float x2 = fminf(A.z, B.z), y2 = fminf(A.w, B.w);
          float iw = fmaxf(x2 - x1 + 1.f, 0.f), ih = fmaxf(y2 - y1 + 1.f, 0.f);
          float inter = iw * ih;
          float areaB = (B.z - B.x + 1.f) * (B.w - B.y + 1.f);
          ov = (inter / (areaA + areaB - inter)) >= 0.5f;
        }
        uint64_t mask = __ballot(ov);
        if (lane == 0) ov_bits[((size_t)(b * NC + c) << 3) + chunk] = mask;
      }
    }
    return;
  }
  gemm_body(x, tail1, w_lin, part, bid, TILES1, 0);
}

// ---------------------------------------------------------------------------
// k_dists: hidden = sum of 8 GEMM1 partials + b_lin (LDS); obj_dists =
// hidden @ w_out + b_out -> d_out; softmax; emit per-row SORTED key list
// (value desc, col asc), cols 1..150:
// skeys[r][rank] = (f2ord(v)<<17) | ((511-r)<<8) | col.
// ---------------------------------------------------------------------------
__global__ __launch_bounds__(256) void k_dists(
    const float* __restrict__ part, const float* __restrict__ b_lin,
    const float* __restrict__ w_out, const float* __restrict__ b_out,
    float* __restrict__ out_dists, uint64_t* __restrict__ skeys) {
  int r = blockIdx.x, t = threadIdx.x;
  __shared__ float h[DH];
  __shared__ float red[256];
  __shared__ float sval[NC];
  float s0 = b_lin[t], s1 = b_lin[t + 256];
#pragma unroll
  for (int z = 0; z < SPLITK; z++) {
    const float* pr = part + ((size_t)z * NB + r) * DH;
    s0 += pr[t]; s1 += pr[t + 256];
  }
  h[t] = s0; h[t + 256] = s1;
  __syncthreads();

  float acc = -INFINITY;
  if (t < NC) {
    acc = b_out[t];
    for (int k = 0; k < DH; k++) acc += h[k] * w_out[k * NC + t];
    out_dists[r * NC + t] = acc;
  }
  red[t] = (t < NC) ? acc : -INFINITY; __syncthreads();
  for (int s = 128; s > 0; s >>= 1) { if (t < s) red[t] = fmaxf(red[t], red[t + s]); __syncthreads(); }
  float mx = red[0]; __syncthreads();
  float e = (t < NC) ? expf(acc - mx) : 0.f;
  red[t] = e; __syncthreads();
  for (int s = 128; s > 0; s >>= 1) { if (t < s) red[t] += red[t + s]; __syncthreads(); }
  float sum = red[0];
  if (t < NC) sval[t] = e / sum;
  __syncthreads();

  if (t >= 1 && t < NC) {
    float v = sval[t];
    int rank = 0;
    for (int c2 = 1; c2 < NC; c2++) {
      float v2 = sval[c2];
      rank += (v2 > v) || (v2 == v && c2 < t);
    }
    skeys[(size_t)r * SKSTRIDE + rank] =
        ((uint64_t)f2ord(v) << 17) | ((uint64_t)(511 - r) << 8) | (uint64_t)t;
  }
}

// ---------------------------------------------------------------------------
// k_nms_g2a: block 0 = greedy NMS (wave 0, top-8 speculation, LDS-staged
// overlap rows, supp masks in LDS); blocks 1..1664 = GEMM2a partials over
// K in [0,4224), hidden under the serial NMS latency.
// ---------------------------------------------------------------------------
__global__ __launch_bounds__(256) void k_nms_g2a(
    const uint64_t* __restrict__ ov_bits, const uint64_t* __restrict__ skeys,
    int* __restrict__ labels_g, float* __restrict__ out_preds,
    const float* __restrict__ x, const float* __restrict__ tail1,
    const float* __restrict__ w_fc, float* __restrict__ part) {
  if (blockIdx.x > 0) {
    gemm_body(x, tail1, w_fc, part, blockIdx.x - 1, TILES2, DE);
    return;
  }
  __shared__ uint64_t stageL[64];       // 8 picks x 8 (7 used) staged ov rows
  __shared__ uint64_t suppL[448 * 3];   // per-row 151-bit suppression masks

  int tid = threadIdx.x;
  for (int i = tid; i < 448 * 3; i += 256) suppL[i] = 0;
  for (int r = tid; r < NB; r += 256) { labels_g[r] = 0; out_preds[r] = 0.f; }
  __syncthreads();
  if (tid >= 64) return;
  int lane = tid;

  const uint64_t SENTV = ((uint64_t)0x407FFFFFu << 17);  // f2ord(-1.0)
  const uint64_t RESV  = ((uint64_t)0x80000000u << 17);  // f2ord(0.0)

  uint64_t cand[SLOTS];
  int depth[SLOTS], reszmin[SLOTS];
  uint32_t remmask = 0;
#pragma unroll
  for (int s = 0; s < SLOTS; s++) {
    int r = s * 64 + lane;
    cand[s] = (r < NB) ? skeys[(size_t)r * SKSTRIDE] : 0;
    depth[s] = 0; reszmin[s] = 255;
  }

  int picked = 0;
  while (picked < NB) {
    // --- local sort of my 7 candidates, descending (odd-even transposition)
    uint64_t a[8];
#pragma unroll
    for (int s = 0; s < SLOTS; s++) a[s] = cand[s];
    a[7] = 0;
#pragma unroll
    for (int rd = 0; rd < 7; rd++) {
      if (rd & 1) { CSW(a[1], a[2]); CSW(a[3], a[4]); CSW(a[5], a[6]); }
      else        { CSW(a[0], a[1]); CSW(a[2], a[3]); CSW(a[4], a[5]); }
    }
    // --- butterfly top-8 merge of sorted lists (bitonic)
#pragma unroll
    for (int off = 1; off < 64; off <<= 1) {
      uint64_t p[8], t8[8];
#pragma unroll
      for (int i = 0; i < 8; i++)
        p[i] = (uint64_t)__shfl_xor((unsigned long long)a[i], off, 64);
#pragma unroll
      for (int i = 0; i < 8; i++) { uint64_t q = p[7 - i]; t8[i] = a[i] > q ? a[i] : q; }
      CSW(t8[0], t8[4]); CSW(t8[1], t8[5]); CSW(t8[2], t8[6]); CSW(t8[3], t8[7]);
      CSW(t8[0], t8[2]); CSW(t8[1], t8[3]); CSW(t8[4], t8[6]); CSW(t8[5], t8[7]);
      CSW(t8[0], t8[1]); CSW(t8[2], t8[3]); CSW(t8[4], t8[5]); CSW(t8[6], t8[7]);
#pragma unroll
      for (int i = 0; i < 8; i++) a[i] = t8[i];
    }
    int bb[8], cc[8];
#pragma unroll
    for (int i = 0; i < 8; i++) {
      bb[i] = 511 - (int)((a[i] >> 8) & 0x1FF);
      cc[i] = (int)(a[i] & 0xFF);
    }
    int npick = NB - picked; if (npick > 8) npick = 8;

    // --- stage the npick winners' overlap rows into LDS
    int pi = lane >> 3, pw = lane & 7;
    if (pi < npick && pw < 7)
      stageL[(pi << 3) + pw] = ov_bits[(((size_t)(bb[pi] * NC + cc[pi])) << 3) + pw];

    // --- validity prefix: pick j ok iff value>0 and no earlier pick i
    //     touched its entry (c_i==c_j && ov_i[b_j]). All lanes compute same.
    int napply = 1;
    for (int j = 1; j < 8; j++) {
      if (j >= npick) break;
      if ((uint32_t)(a[j] >> 17) <= 0x80000000u) break;
      bool ok = true;
      for (int i = 0; i < j; i++) {
        if (cc[i] == cc[j]) {
          uint64_t wv = stageL[(i << 3) + (bb[j] >> 6)];
          if ((wv >> (bb[j] & 63)) & 1) ok = false;
        }
      }
      if (!ok) break;
      napply = j + 1;
    }

    // --- per-slot register updates, pick-order within each row
#pragma unroll
    for (int s = 0; s < SLOTS; s++) {
      int r = s * 64 + lane;
      uint64_t w[8];
#pragma unroll
      for (int i = 0; i < 8; i++) w[i] = (i < napply) ? stageL[(i << 3) + s] : 0;
      uint64_t cv = cand[s];
      bool rem = (remmask >> s) & 1;
      int rm = reszmin[s], dp = depth[s];
#pragma unroll
      for (int i = 0; i < 8; i++) {
        if (i >= napply) break;
        int b = bb[i], c = cc[i];
        if (r == b) {
          rem = true; rm = 255;
          cv = SENTV | ((uint64_t)(511 - r) << 8);
        } else if ((w[i] >> lane) & 1) {
          if (rem) {
            if (c < rm) rm = c;
            cv = RESV | ((uint64_t)(511 - r) << 8) | (uint64_t)rm;
          } else {
            int wo = c >> 6;
            uint64_t sb = suppL[r * 3 + wo] | (1ull << (c & 63));
            suppL[r * 3 + wo] = sb;
            if ((int)(cv & 0xFF) == c) {
              // suppressed entry was this row's argmax -> pop sorted list
              int d = dp + 1;
              uint64_t nk = 0;
              for (; d < 150; d++) {
                nk = skeys[(size_t)r * SKSTRIDE + d];
                int col = (int)(nk & 0xFF);
                uint64_t m = suppL[r * 3 + (col >> 6)];
                if (!((m >> (col & 63)) & 1)) break;
              }
              if (d >= 150)  // all cols 1..150 suppressed -> (0.0, col 1)
                nk = RESV | ((uint64_t)(511 - r) << 8) | 1ull;
              dp = d; cv = nk;
            }
          }
        }
      }
      cand[s] = cv; reszmin[s] = rm; depth[s] = dp;
      if (rem) remmask |= (1u << s);
    }
    // --- labels for applied picks
#pragma unroll
    for (int i = 0; i < 8; i++) {
      if (i < napply && lane == i) {
        labels_g[bb[i]] = cc[i];
        out_preds[bb[i]] = (float)cc[i];
      }
    }
    picked += napply;
  }
}

// ---------------------------------------------------------------------------
// k_final: edge_ctx = relu( GEMM2a-partials + emb2[labels] @ w_fc[4224:] +
// b_fc ). Grid (8 n, 13 m); 32x64 tile over K=200 with label-gathered A.
// ---------------------------------------------------------------------------
__global__ __launch_bounds__(256) void k_final(
    const float* __restrict__ emb2, const int* __restrict__ labels,
    const float* __restrict__ w_fc, const float* __restrict__ part,
    const float* __restrict__ b_fc, float* __restrict__ out_edge) {
  __shared__ __align__(16) float As[32][36];
  __shared__ __align__(16) float Bs[32][68];
  int tid = threadIdx.x;
  int n0 = blockIdx.x * 64, m0 = blockIdx.y * 32;
  int ty = tid >> 4, tx = tid & 15;
  int a_r = tid >> 3, a_c = (tid & 7) << 2;
  int b_r = tid >> 4, b_c = (tid & 15) << 2;
  float4 acc0 = {0, 0, 0, 0}, acc1 = {0, 0, 0, 0};
  int row_a = m0 + a_r;
  int lab = (row_a < NB) ? labels[row_a] : 0;

  auto loadA = [&](int t) -> float4 {
    int kk = t * 32 + a_c;
    float4 v = {0, 0, 0, 0};
    if (kk < DE && row_a < NB) v = *(const float4*)&emb2[(size_t)lab * DE + kk];
    return v;
  };
  auto loadB = [&](int t, int roff) -> float4 {
    int kk = t * 32 + b_r + roff;
    float4 v = {0, 0, 0, 0};
    if (kk < DE) v = *(const float4*)&w_fc[(size_t)(DX + DP + kk) * DH + n0 + b_c];
    return v;
  };

  float4 pa = loadA(0), pb0 = loadB(0, 0), pb1 = loadB(0, 16);
  for (int t = 0; t < 7; t++) {   // 7 tiles cover K=200 (guards handle tail)
    __syncthreads();
    *(float4*)&As[a_r][a_c] = pa;
    *(float4*)&Bs[b_r][b_c] = pb0;
    *(float4*)&Bs[b_r + 16][b_c] = pb1;
    __syncthreads();
    if (t + 1 < 7) { pa = loadA(t + 1); pb0 = loadB(t + 1, 0); pb1 = loadB(t + 1, 16); }
#pragma unroll
    for (int k4 = 0; k4 < 8; k4++) {
      float4 a0 = *(float4*)&As[ty * 2][k4 * 4];
      float4 a1 = *(float4*)&As[ty * 2 + 1][k4 * 4];
#pragma unroll
      for (int j = 0; j < 4; j++) {
        float4 bv = *(float4*)&Bs[k4 * 4 + j][tx * 4];
        float av0 = (&a0.x)[j], av1 = (&a1.x)[j];
        acc0.x += av0 * bv.x; acc0.y += av0 * bv.y; acc0.z += av0 * bv.z; acc0.w += av0 * bv.w;
        acc1.x += av1 * bv.x; acc1.y += av1 * bv.y; acc1.z += av1 * bv.z; acc1.w += av1 * bv.w;
      }
    }
  }
  int row0 = m0 + ty * 2, col = n0 + tx * 4;
#pragma unroll
  for (int z = 0; z < SPLITK; z++) {
    if (row0 < NB) {
      float4 p = *(const float4*)&part[((size_t)z * NB + row0) * DH + col];
      acc0.x += p.x; acc0.y += p.y; acc0.z += p.z; acc0.w += p.w;
    }
    if (row0 + 1 < NB) {
      float4 p = *(const float4*)&part[((size_t)z * NB + row0 + 1) * DH + col];
      acc1.x += p.x; acc1.y += p.y; acc1.z += p.z; acc1.w += p.w;
    }
  }
  float4 bv = *(const float4*)&b_fc[col];
  if (row0 < NB) {
    float4 r;
    r.x = fmaxf(acc0.x + bv.x, 0.f); r.y = fmaxf(acc0.y + bv.y, 0.f);
    r.z = fmaxf(acc0.z + bv.z, 0.f); r.w = fmaxf(acc0.w + bv.w, 0.f);
    *(float4*)&out_edge[row0 * DH + col] = r;
  }
  if (row0 + 1 < NB) {
    float4 r;
    r.x = fmaxf(acc1.x + bv.x, 0.f); r.y = fmaxf(acc1.y + bv.y, 0.f);
    r.z = fmaxf(acc1.z + bv.z, 0.f); r.w = fmaxf(acc1.w + bv.w, 0.f);
    *(float4*)&out_edge[(row0 + 1) * DH + col] = r;
  }
}

// ---------------------------------------------------------------------------
extern "C" void kernel_launch(void* const* d_in, const int* in_sizes, int n_in,
                              void* d_out, int out_size, void* d_ws, size_t ws_size,
                              hipStream_t stream) {
  const float* x            = (const float*)d_in[0];
  const float* logits       = (const float*)d_in[1];
  const float* pos_input    = (const float*)d_in[2];
  const float* boxes        = (const float*)d_in[3];
  const float* obj_embed_w  = (const float*)d_in[4];
  const float* obj_embed2_w = (const float*)d_in[5];
  const float* w_pos1       = (const float*)d_in[6];
  const float* b_pos1       = (const float*)d_in[7];
  const float* bn_gamma     = (const float*)d_in[8];
  const float* bn_beta      = (const float*)d_in[9];
  const float* bn_mean      = (const float*)d_in[10];
  const float* bn_var       = (const float*)d_in[11];
  const float* w_pos2       = (const float*)d_in[12];
  const float* b_pos2       = (const float*)d_in[13];
  const float* w_lin        = (const float*)d_in[14];
  const float* b_lin        = (const float*)d_in[15];
  const float* w_out        = (const float*)d_in[16];
  const float* b_out        = (const float*)d_in[17];
  const float* w_fc         = (const float*)d_in[18];
  const float* b_fc         = (const float*)d_in[19];

  float* ws         = (float*)d_ws;
  float* tail1      = ws;                              // 416*328 floats
  int* labels       = (int*)(tail1 + MPAD * TAILW);    // 416 ints (even offset)
  uint64_t* skeys   = (uint64_t*)(labels + MPAD);      // 400*152 u64
  uint64_t* ov_bits = skeys + (size_t)NB * SKSTRIDE;   // 400*151*8 u64
  float* part       = (float*)(ov_bits + (size_t)NB * NC * 8);  // 8*400*512 f

  float* out       = (float*)d_out;
  float* out_dists = out;                 // 400*151
  float* out_preds = out + NB * NC;       // 400
  float* out_edge  = out + NB * NC + NB;  // 400*512

  k_embed<<<MPAD, 256, 0, stream>>>(logits, obj_embed_w, pos_input, w_pos1, b_pos1,
                                    bn_gamma, bn_beta, bn_mean, bn_var, w_pos2, b_pos2,
                                    tail1);
  k_g1ov<<<NGB + NC, 256, 0, stream>>>(x, tail1, w_lin, part, boxes, ov_bits);
  k_dists<<<NB, 256, 0, stream>>>(part, b_lin, w_out, b_out, out_dists, skeys);
  k_nms_g2a<<<NGB + 1, 256, 0, stream>>>(ov_bits, skeys, labels, out_preds,
                                         x, tail1, w_fc, part);
  k_final<<<dim3(8, 13), 256, 0, stream>>>(obj_embed2_w, labels, w_fc, part,
                                           b_fc, out_edge);
}